// Round 3
// baseline (277.409 us; speedup 1.0000x reference)
//
#include <hip/hip_runtime.h>
#include <math.h>

#define N_NODES 128
#define IN_DIM  512
#define MEM     256
#define HID     128
#define NCLS    5

// ws layout (float offsets)
#define IOUX_OFF 0                      // 2 * 128 * 768
#define FX_OFF   196608                 // 2 * 129 * 256
#define H_OFF    262656                 // 2 * 128 * 256
#define BAR_OFF  328192                 // barrier counters: 2 trees * 128 lvls * 16 ints

__device__ __forceinline__ float sigmf(float x) {
    return 1.0f / (1.0f + __expf(-x));
}
__device__ __forceinline__ float tanh_fast(float x) {
    float e = __expf(2.0f * x);
    return 1.0f - 2.0f / (e + 1.0f);
}

// ---------------------------------------------------------------------------
// K1: input GEMM, register-tiled, no LDS.
// 128 blocks = 8 row-tiles(32) x 16 col-tiles(64). 256 threads = 4 waves,
// each wave: 8 rows x 64 cols. A (emb rows) via wave-uniform scalar loads.
// Block 0 additionally zeroes the k2 barrier counters (before k2 launches).
// ---------------------------------------------------------------------------
__global__ __launch_bounds__(256) void k1_gemm(
        const float* __restrict__ emb,
        const float* __restrict__ Wioux, const float* __restrict__ bioux,
        const float* __restrict__ Wfx,   const float* __restrict__ bfx,
        const int* __restrict__ linputs, const int* __restrict__ rinputs,
        float* __restrict__ ws) {
    int bid = blockIdx.x;
    int tid = threadIdx.x;
    if (bid == 0) {
        int* bar = (int*)(ws + BAR_OFF);
        for (int i = tid; i < 4096; i += 256) bar[i] = 0;
    }
    int r0 = (bid >> 4) * 32;
    int c0 = (bid & 15) * 64;
    int rb = r0 + ((tid >> 6) << 3);       // first of this wave's 8 rows
    int c  = c0 + (tid & 63);
    bool isio = (c0 < 768);
    const float* Bp; int ldb;
    if (isio) { Bp = Wioux + c; ldb = 768; }
    else      { Bp = Wfx + (c - 768); ldb = 256; }

    int tk[8];
    #pragma unroll
    for (int i = 0; i < 8; i++) {
        int row = rb + i;
        int t = (row < 128) ? linputs[row] : rinputs[row - 128];
        tk[i] = __builtin_amdgcn_readfirstlane(t);
    }
    float acc[8] = {0.f,0.f,0.f,0.f,0.f,0.f,0.f,0.f};
    for (int k = 0; k < 512; k += 4) {
        float b0 = Bp[(size_t)(k + 0) * ldb];
        float b1 = Bp[(size_t)(k + 1) * ldb];
        float b2 = Bp[(size_t)(k + 2) * ldb];
        float b3 = Bp[(size_t)(k + 3) * ldb];
        #pragma unroll
        for (int i = 0; i < 8; i++) {
            const float* ar = emb + (size_t)tk[i] * 512 + k;
            acc[i] = fmaf(ar[0], b0, fmaf(ar[1], b1,
                     fmaf(ar[2], b2, fmaf(ar[3], b3, acc[i]))));
        }
    }
    #pragma unroll
    for (int i = 0; i < 8; i++) {
        int row = rb + i;
        int tree = row >> 7, node = row & 127;
        if (isio) ws[IOUX_OFF + (size_t)row * 768 + c] = acc[i] + bioux[c];
        else      ws[FX_OFF + ((size_t)tree * 129 + node) * 256 + (c - 768)]
                      = acc[i] + bfx[c - 768];
    }
}

// ---------------------------------------------------------------------------
// K2: level-order TreeLSTM. 32 blocks (16/tree) x 256 threads.
// Block owns 16 j-columns, weights in registers. Forget-gates computed
// just-in-time during the parent's gather (no FC in global, no phase B).
// One custom 16-block barrier per level.
// ---------------------------------------------------------------------------
__global__ __launch_bounds__(256, 1) void k2_scan(
        const float* __restrict__ Wiouh, const float* __restrict__ biouh,
        const float* __restrict__ Wfh,   const float* __restrict__ bfh,
        const int* __restrict__ lparents, const int* __restrict__ rparents,
        float* __restrict__ ws) {
    int bid = blockIdx.x;
    int tree = bid >> 4;
    int slice = (bid & 15) * 16;
    const int* parents = tree ? rparents : lparents;
    const float* ioux = ws + IOUX_OFF + (size_t)tree * 128 * 768;
    const float* fx   = ws + FX_OFF   + (size_t)tree * 129 * 256;
    float* H = ws + H_OFF + (size_t)tree * 128 * 256;
    int* bar = (int*)(ws + BAR_OFF) + tree * 2048;   // 128 lvls * 16 ints

    // h rows live at group stride 17: kmap(k) = (k>>4)*17 + (k&15)
    __shared__ float hsin[16][272];
    __shared__ float hv[16][272];
    __shared__ float red[4][3][16][17];
    __shared__ float cc[128][17];
    __shared__ float FCtmp[16][17];
    __shared__ float fcin[16][17];
    __shared__ int clist[128], cslot[128], cpar[128];
    __shared__ int order[128], rstart[129], kids[128], kstart[129];
    __shared__ int coff[17];
    __shared__ int changed;

    // prologue-only temporaries aliased into hv
    int* par = (int*)&hv[0][0];     // 128
    int* rnd = (int*)&hv[1][0];     // 128
    int* cnt = (int*)&hv[2][0];     // 129

    int tid = threadIdx.x;
    int nq = tid >> 4;       // node-slot / k-group (16 x 16)
    int j  = tid & 15;
    int jcol = slice + j;

    // ---- weights into registers (whole kernel) ----
    float Wi[16], Wo[16], Wu[16], Wf[16];
    #pragma unroll
    for (int kk = 0; kk < 16; kk++) {
        int k = nq * 16 + kk;
        Wi[kk] = Wiouh[k * 768 + jcol];
        Wo[kk] = Wiouh[k * 768 + 256 + jcol];
        Wu[kk] = Wiouh[k * 768 + 512 + jcol];
        Wf[kk] = Wfh[k * 256 + jcol];
    }
    float bio0 = biouh[jcol], bio1 = biouh[256 + jcol], bio2 = biouh[512 + jcol];
    float bfr = bfh[jcol];

    // ---- prologue: levels via relaxation ----
    if (tid < 128) { par[tid] = parents[tid]; rnd[tid] = 0; }
    __syncthreads();
    for (;;) {
        if (tid == 0) changed = 0;
        __syncthreads();
        if (tid < 128) {
            int p = par[tid];
            if (p < 128) {
                int v = rnd[tid] + 1;
                if (atomicMax(&rnd[p], v) < v) changed = 1;
            }
        }
        __syncthreads();
        int done = (changed == 0);
        __syncthreads();
        if (done) break;
    }
    int nr = rnd[127] + 1;    // root carries the max level

    // counting sort nodes by level (stable)
    if (tid <= 128) cnt[tid] = 0;
    __syncthreads();
    if (tid < 128) atomicAdd(&cnt[rnd[tid]], 1);
    __syncthreads();
    if (tid == 0) {
        int a = 0;
        for (int rr = 0; rr < 128; rr++) { rstart[rr] = a; a += cnt[rr]; }
        rstart[128] = a;
    }
    __syncthreads();
    if (tid < 128) {
        int rr = rnd[tid], rk = 0;
        for (int t2 = 0; t2 < tid; t2++) rk += (rnd[t2] == rr) ? 1 : 0;
        order[rstart[rr] + rk] = tid;
    }
    __syncthreads();
    // children adjacency (stable)
    if (tid <= 128) cnt[tid] = 0;
    __syncthreads();
    if (tid < 128) atomicAdd(&cnt[par[tid]], 1);
    __syncthreads();
    if (tid == 0) {
        int a = 0;
        for (int t = 0; t <= 128; t++) { kstart[t] = a; a += cnt[t]; }
    }
    __syncthreads();
    if (tid < 128) {
        int p = par[tid], rk = 0;
        for (int t2 = 0; t2 < tid; t2++) rk += (par[t2] == p) ? 1 : 0;
        kids[kstart[p] + rk] = tid;
    }
    __syncthreads();

    int km = nq * 17 + j;     // this thread's swizzled k position

    // ---- main level loop ----
    for (int r = 0; r < nr; r++) {
        int rs = rstart[r], re = rstart[r + 1];
        if (r == 0) {
            // leaves: pure elementwise on ioux (no children, no matvec)
            for (int b0 = rs; b0 < re; b0 += 16) {
                int t = -1;
                if (b0 + nq < re) t = order[b0 + nq];
                if (t >= 0) {
                    float iv = ioux[t * 768 + jcol]       + bio0;
                    float ov = ioux[t * 768 + 256 + jcol] + bio1;
                    float uv = ioux[t * 768 + 512 + jcol] + bio2;
                    float cv = sigmf(iv) * tanh_fast(uv);
                    float h  = sigmf(ov) * tanh_fast(cv);
                    cc[t][j] = cv;
                    H[t * 256 + jcol] = h;
                }
            }
        } else {
            for (int b0 = rs; b0 < re; b0 += 16) {
                int nn = re - b0; if (nn > 16) nn = 16;
                // zero accumulators
                #pragma unroll
                for (int n2 = 0; n2 < 16; n2++) hsin[n2][km] = 0.f;
                fcin[nq][j] = 0.f;
                // build flat children list of this node-batch
                if (tid < 16) {
                    int cctn = 0;
                    if (tid < nn) {
                        int t = order[b0 + tid];
                        cctn = kstart[t + 1] - kstart[t];
                    }
                    coff[tid] = cctn;
                }
                __syncthreads();
                if (tid == 0) {
                    int a = 0;
                    for (int i2 = 0; i2 < 16; i2++) { int v = coff[i2]; coff[i2] = a; a += v; }
                    coff[16] = a;
                }
                __syncthreads();
                if (tid < nn) {
                    int t = order[b0 + tid];
                    int o = coff[tid];
                    for (int ci = kstart[t]; ci < kstart[t + 1]; ci++, o++) {
                        clist[o] = kids[ci]; cslot[o] = tid; cpar[o] = t;
                    }
                }
                __syncthreads();
                int M = coff[16];

                // ---- child sub-batches: JIT forget gates + gather ----
                for (int cb = 0; cb < M; cb += 16) {
                    int mm = M - cb; if (mm > 16) mm = 16;
                    int chn = -1; float fxv = 0.f;
                    if (nq < mm) {
                        chn = clist[cb + nq];
                        fxv = fx[cpar[cb + nq] * 256 + jcol];
                    }
                    {   // load h rows (thread role: node nq, k-chunk j)
                        float4 g0, g1, g2, g3;
                        if (chn >= 0) {
                            const float4* hp = (const float4*)(H + chn * 256 + j * 16);
                            g0 = hp[0]; g1 = hp[1]; g2 = hp[2]; g3 = hp[3];
                        } else {
                            g0 = g1 = g2 = g3 = make_float4(0.f, 0.f, 0.f, 0.f);
                        }
                        float* row = &hv[nq][j * 17];
                        row[0]=g0.x;  row[1]=g0.y;  row[2]=g0.z;  row[3]=g0.w;
                        row[4]=g1.x;  row[5]=g1.y;  row[6]=g1.z;  row[7]=g1.w;
                        row[8]=g2.x;  row[9]=g2.y;  row[10]=g2.z; row[11]=g2.w;
                        row[12]=g3.x; row[13]=g3.y; row[14]=g3.z; row[15]=g3.w;
                    }
                    __syncthreads();
                    // f matvec over own 16-k group
                    float af[16];
                    #pragma unroll
                    for (int n2 = 0; n2 < 16; n2++) {
                        float a = 0.f;
                        const float* row = &hv[n2][nq * 17];
                        #pragma unroll
                        for (int kk = 0; kk < 16; kk++) a = fmaf(Wf[kk], row[kk], a);
                        af[n2] = a;
                    }
                    #pragma unroll
                    for (int n2 = 0; n2 < 16; n2++) {
                        af[n2] += __shfl_xor(af[n2], 16);
                        af[n2] += __shfl_xor(af[n2], 32);
                    }
                    {
                        int w = tid >> 6;
                        #pragma unroll
                        for (int n2 = 0; n2 < 16; n2++) red[w][0][n2][j] = af[n2];
                    }
                    __syncthreads();
                    if (nq < mm) {
                        float sf = red[0][0][nq][j] + red[1][0][nq][j]
                                 + red[2][0][nq][j] + red[3][0][nq][j];
                        float f = sigmf(sf + bfr + fxv);
                        FCtmp[nq][j] = f * cc[chn][j];
                    }
                    __syncthreads();
                    // deterministic accumulate into parent slots
                    for (int n2 = 0; n2 < mm; n2++) {
                        int sl = cslot[cb + n2];
                        hsin[sl][km] += hv[n2][km];
                        if (tid < 16) fcin[sl][tid] += FCtmp[n2][tid];
                    }
                    __syncthreads();
                }

                // ---- iou matvec + gates ----
                float io0 = 0.f, io1 = 0.f, io2 = 0.f; int tn = -1;
                if (nq < nn) {
                    tn = order[b0 + nq];
                    io0 = ioux[tn * 768 + jcol];
                    io1 = ioux[tn * 768 + 256 + jcol];
                    io2 = ioux[tn * 768 + 512 + jcol];
                }
                float ai[16], ao[16], au[16];
                #pragma unroll
                for (int n2 = 0; n2 < 16; n2++) {
                    float a = 0.f, b = 0.f, c2 = 0.f;
                    const float* row = &hsin[n2][nq * 17];
                    #pragma unroll
                    for (int kk = 0; kk < 16; kk++) {
                        float v = row[kk];
                        a  = fmaf(Wi[kk], v, a);
                        b  = fmaf(Wo[kk], v, b);
                        c2 = fmaf(Wu[kk], v, c2);
                    }
                    ai[n2] = a; ao[n2] = b; au[n2] = c2;
                }
                #pragma unroll
                for (int n2 = 0; n2 < 16; n2++) {
                    ai[n2] += __shfl_xor(ai[n2], 16); ai[n2] += __shfl_xor(ai[n2], 32);
                    ao[n2] += __shfl_xor(ao[n2], 16); ao[n2] += __shfl_xor(ao[n2], 32);
                    au[n2] += __shfl_xor(au[n2], 16); au[n2] += __shfl_xor(au[n2], 32);
                }
                {
                    int w = tid >> 6;
                    #pragma unroll
                    for (int n2 = 0; n2 < 16; n2++) {
                        red[w][0][n2][j] = ai[n2];
                        red[w][1][n2][j] = ao[n2];
                        red[w][2][n2][j] = au[n2];
                    }
                }
                __syncthreads();
                if (tn >= 0) {
                    float si = red[0][0][nq][j] + red[1][0][nq][j]
                             + red[2][0][nq][j] + red[3][0][nq][j];
                    float so = red[0][1][nq][j] + red[1][1][nq][j]
                             + red[2][1][nq][j] + red[3][1][nq][j];
                    float su = red[0][2][nq][j] + red[1][2][nq][j]
                             + red[2][2][nq][j] + red[3][2][nq][j];
                    float iv = si + io0 + bio0;
                    float ov = so + io1 + bio1;
                    float uv = su + io2 + bio2;
                    float cv = fmaf(sigmf(iv), tanh_fast(uv), fcin[nq][j]);
                    float h  = sigmf(ov) * tanh_fast(cv);
                    cc[tn][j] = cv;
                    H[tn * 256 + jcol] = h;
                }
                __syncthreads();
            }
        }
        if (r < nr - 1) {
            // custom 16-block tree barrier, fresh counter per level
            __syncthreads();
            if (tid == 0) {
                __threadfence();
                int* cp = bar + r * 16;
                __hip_atomic_fetch_add(cp, 1, __ATOMIC_ACQ_REL, __HIP_MEMORY_SCOPE_AGENT);
                while (__hip_atomic_load(cp, __ATOMIC_ACQUIRE, __HIP_MEMORY_SCOPE_AGENT) < 16) {}
            }
            __syncthreads();
        }
    }
}

// ---------------------------------------------------------------------------
// K3: attention (root rows only) + classifier head. 1 block, 256 threads.
// ---------------------------------------------------------------------------
__global__ __launch_bounds__(256) void k3_head(
        const float* __restrict__ Wattn, const float* __restrict__ battn,
        const float* __restrict__ Wwh,   const float* __restrict__ bwh,
        const float* __restrict__ Wwp,   const float* __restrict__ bwp,
        const float* __restrict__ ws, float* __restrict__ out) {
    const float* Hl = ws + H_OFF;
    const float* Hr = ws + H_OFF + 128 * 256;

    __shared__ float hlroot[MEM], hrroot[MEM];
    __shared__ float s[N_NODES], sc[N_NODES];
    __shared__ float beta[MEM], alpha[MEM];
    __shared__ float vl[MEM], vr[MEM];
    __shared__ float vec[2 * MEM];
    __shared__ float hid[HID];

    int tid = threadIdx.x;
    hlroot[tid] = Hl[127 * MEM + tid];
    hrroot[tid] = Hr[127 * MEM + tid];
    __syncthreads();

    if (tid < 128) {
        float a = 0.f;
        for (int k = 0; k < MEM; k++) a = fmaf(hlroot[k], Hr[tid * MEM + k], a);
        s[tid] = a;
    } else {
        int i = tid - 128; float a = 0.f;
        for (int k = 0; k < MEM; k++) a = fmaf(Hl[i * MEM + k], hrroot[k], a);
        sc[i] = a;
    }
    __syncthreads();

    if (tid < 2) {
        float* v = tid ? sc : s;
        float m = -1e30f;
        for (int k = 0; k < 128; k++) m = fmaxf(m, v[k]);
        float su = 0.f;
        for (int k = 0; k < 128; k++) { float e = __expf(v[k] - m); v[k] = e; su += e; }
        float inv = 1.0f / su;
        for (int k = 0; k < 128; k++) v[k] *= inv;
    }
    __syncthreads();

    {
        float b = 0.f, a2 = 0.f;
        for (int jj = 0; jj < 128; jj++) {
            b  = fmaf(s[jj],  Hr[jj * MEM + tid], b);
            a2 = fmaf(sc[jj], Hl[jj * MEM + tid], a2);
        }
        beta[tid] = b; alpha[tid] = a2;
    }
    __syncthreads();

    {
        float a = 0.f, b = 0.f;
        for (int k = 0; k < MEM; k++) {
            float w = Wattn[k * MEM + tid];
            a = fmaf(hlroot[k], w, a);
            b = fmaf(hrroot[k], w, b);
        }
        for (int k = 0; k < MEM; k++) {
            float w = Wattn[(MEM + k) * MEM + tid];
            a = fmaf(beta[k],  w, a);
            b = fmaf(alpha[k], w, b);
        }
        vl[tid] = a + battn[tid];
        vr[tid] = b + battn[tid];
    }
    __syncthreads();

    vec[tid]       = vl[tid] * vr[tid];
    vec[MEM + tid] = fabsf(vl[tid] - vr[tid]);
    __syncthreads();

    if (tid < HID) {
        float a = 0.f;
        for (int k = 0; k < 2 * MEM; k++) a = fmaf(vec[k], Wwh[k * HID + tid], a);
        hid[tid] = sigmf(a + bwh[tid]);
    }
    __syncthreads();

    if (tid == 0) {
        float lg[NCLS];
        for (int c = 0; c < NCLS; c++) {
            float a = bwp[c];
            for (int k = 0; k < HID; k++) a = fmaf(hid[k], Wwp[k * NCLS + c], a);
            lg[c] = a;
        }
        float m = lg[0];
        for (int c = 1; c < NCLS; c++) m = fmaxf(m, lg[c]);
        float su = 0.f;
        for (int c = 0; c < NCLS; c++) su += __expf(lg[c] - m);
        float lse = logf(su);
        for (int c = 0; c < NCLS; c++) out[c] = lg[c] - m - lse;
    }
}

extern "C" void kernel_launch(void* const* d_in, const int* in_sizes, int n_in,
                              void* d_out, int out_size, void* d_ws, size_t ws_size,
                              hipStream_t stream) {
    const float* emb    = (const float*)d_in[0];
    const float* Wioux  = (const float*)d_in[1];
    const float* bioux  = (const float*)d_in[2];
    const float* Wiouh  = (const float*)d_in[3];
    const float* biouh  = (const float*)d_in[4];
    const float* Wfx    = (const float*)d_in[5];
    const float* bfx    = (const float*)d_in[6];
    const float* Wfh    = (const float*)d_in[7];
    const float* bfh    = (const float*)d_in[8];
    const float* Wattn  = (const float*)d_in[9];
    const float* battn  = (const float*)d_in[10];
    const float* Wwh    = (const float*)d_in[11];
    const float* bwh    = (const float*)d_in[12];
    const float* Wwp    = (const float*)d_in[13];
    const float* bwp    = (const float*)d_in[14];
    const int* linputs  = (const int*)d_in[15];
    const int* lparents = (const int*)d_in[16];
    const int* rinputs  = (const int*)d_in[17];
    const int* rparents = (const int*)d_in[18];
    float* ws  = (float*)d_ws;
    float* out = (float*)d_out;

    k1_gemm<<<128, 256, 0, stream>>>(emb, Wioux, bioux, Wfx, bfx,
                                     linputs, rinputs, ws);
    k2_scan<<<32, 256, 0, stream>>>(Wiouh, biouh, Wfh, bfh,
                                    lparents, rparents, ws);
    k3_head<<<1, 256, 0, stream>>>(Wattn, battn, Wwh, bwh, Wwp, bwp, ws, out);
}

// Round 4
// 269.977 us; speedup vs baseline: 1.0275x; 1.0275x over previous
//
#include <hip/hip_runtime.h>
#include <math.h>

#define NBT 16

// ws byte offsets
#define H2_BYTE   0           // ull[2][128][128]  = 256 KB  (h pairs, atomic-only)
#define IOUX_BYTE 262144      // float[2][16][128][64] = 1 MB (k1 -> k2, block-grouped)
#define BAR_BYTE  1310720     // int[512]: [tree][128] level counters + fin at [256]

__device__ __forceinline__ float sigmf(float x){ return 1.0f/(1.0f+__expf(-x)); }
__device__ __forceinline__ float tanh_fast(float x){ float e=__expf(2.0f*x); return 1.0f - 2.0f/(e+1.0f); }
__device__ __forceinline__ unsigned long long packf2(float lo, float hi){
    union{ float f[2]; unsigned long long u; } x; x.f[0]=lo; x.f[1]=hi; return x.u;
}
__device__ __forceinline__ unsigned long long aload(unsigned long long* p){
    return __hip_atomic_load(p, __ATOMIC_RELAXED, __HIP_MEMORY_SCOPE_AGENT);
}
__device__ __forceinline__ void astore(unsigned long long* p, unsigned long long v){
    __hip_atomic_store(p, v, __ATOMIC_RELAXED, __HIP_MEMORY_SCOPE_AGENT);
}

// ---------------------------------------------------------------------------
// K1: input GEMM. 128 blocks = tree(2) x sub(16) x q(4); 256 threads.
// Block computes nodes [q*32, q*32+32) x the 64 cols (16i,16o,16u,16f) that
// k2 block (tree,sub) will consume; output grouped so k2's copy is contiguous.
// ---------------------------------------------------------------------------
__global__ __launch_bounds__(256) void k1_gemm(
        const float* __restrict__ emb,
        const float* __restrict__ Wioux, const float* __restrict__ bioux,
        const float* __restrict__ Wfx,   const float* __restrict__ bfx,
        const int* __restrict__ linputs, const int* __restrict__ rinputs,
        float* __restrict__ ws){
    int bid  = blockIdx.x;
    int tree = bid >> 6;
    int sub  = (bid >> 2) & 15;
    int q    = bid & 3;
    int n0   = q * 32;
    const int* inp = tree ? rinputs : linputs;
    float* dst = (float*)((char*)ws + IOUX_BYTE) + (size_t)(tree*16+sub)*128*64;

    __shared__ float Xs[32][513];    // pitch 513: bank = r + ... conflict-free
    __shared__ int toks[32];
    int tid = threadIdx.x;
    if (tid < 32) toks[tid] = inp[n0 + tid];
    __syncthreads();
    {   // stage 32 emb rows
        int r = tid & 31, seg = tid >> 5;      // 2 segs of 64 floats... (8 segs of 64)
        const float* src = emb + (size_t)toks[r]*512 + seg*64;
        #pragma unroll
        for (int ii = 0; ii < 16; ii++){
            float4 v = ((const float4*)src)[ii];
            Xs[r][seg*64 + ii*4 + 0] = v.x;
            Xs[r][seg*64 + ii*4 + 1] = v.y;
            Xs[r][seg*64 + ii*4 + 2] = v.z;
            Xs[r][seg*64 + ii*4 + 3] = v.w;
        }
    }
    __syncthreads();
    int c  = tid & 63;          // 0..63: gate g = c>>4, col jj = c&15
    int ng = tid >> 6;          // 0..3: 8 nodes each
    int g = c >> 4, jj = c & 15;
    const float* Wcol; int ld; float bias;
    if (g < 3){ int col = g*256 + sub*16 + jj; Wcol = Wioux + col; ld = 768; bias = bioux[col]; }
    else      { int col = sub*16 + jj;         Wcol = Wfx + col;   ld = 256; bias = bfx[col]; }
    float acc[8] = {0,0,0,0,0,0,0,0};
    #pragma unroll 4
    for (int k = 0; k < 512; k++){
        float w = Wcol[(size_t)k*ld];
        #pragma unroll
        for (int i = 0; i < 8; i++) acc[i] = fmaf(Xs[ng*8+i][k], w, acc[i]);
    }
    #pragma unroll
    for (int i = 0; i < 8; i++)
        dst[(size_t)(n0 + ng*8 + i)*64 + c] = acc[i] + bias;
}

// ---------------------------------------------------------------------------
// K2: level-order TreeLSTM, 32 blocks (16/tree) x 256 threads, fused head.
// Exchange: H as packed ull via RELAXED agent atomics (no fences, no L2 flush).
// Barrier: per-level counter; __syncthreads drains vmcnt before arrive.
// ---------------------------------------------------------------------------
__global__ __launch_bounds__(256, 1) void k2_scan(
        const float* __restrict__ Wiouh, const float* __restrict__ biouh,
        const float* __restrict__ Wfh,   const float* __restrict__ bfh,
        const int* __restrict__ lparents, const int* __restrict__ rparents,
        const float* __restrict__ Wattn, const float* __restrict__ battn,
        const float* __restrict__ Wwh,   const float* __restrict__ bwh,
        const float* __restrict__ Wwp,   const float* __restrict__ bwp,
        float* __restrict__ ws, float* __restrict__ out){

    int bid = blockIdx.x;
    int tree = bid >> 4;
    int sub  = bid & 15;
    int slice = sub * 16;
    const int* parents = tree ? rparents : lparents;

    unsigned long long* H2all = (unsigned long long*)((char*)ws + H2_BYTE);
    unsigned long long* H2 = H2all + (size_t)tree*128*128;
    const float* iosrc = (const float*)((char*)ws + IOUX_BYTE) + (size_t)(tree*16+sub)*128*64;
    int* bar  = (int*)((char*)ws + BAR_BYTE);
    int* barT = bar + tree*128;
    int* fin  = bar + 256;

    __shared__ float hv[32][272];        // child h rows, swizzled km = (k>>4)*17+(k&15)
    __shared__ float hsin[16][272];      // per-node child-h sums
    __shared__ float red[4][48][17];     // cross-wave reduce
    __shared__ float FCtmp[32][17];
    __shared__ float fcin[16][17];
    __shared__ float cc[128][17];        // c (own cols) per node
    __shared__ float ioufL[128][67];     // cols 0..47 = i|o|u slice, 48..63 = fx slice
    __shared__ float biofL[64];
    __shared__ int par[128], rnd[128], order[128], kids[128];
    __shared__ int rstart[129], kstart[129], cnt[129];
    __shared__ int clist[128], cslot[128], cpar[128];
    __shared__ int coff[17];
    __shared__ int changed;

    int tid = threadIdx.x;
    int a = tid >> 4;       // k-group / node-slot
    int j = tid & 15;
    int jcol = slice + j;

    // ---- recurrence weights -> registers (held whole kernel) ----
    float Wi[16], Wo[16], Wu[16], Wf[16];
    #pragma unroll
    for (int kk = 0; kk < 16; kk++){
        int k = a*16 + kk;
        Wi[kk] = Wiouh[(size_t)k*768 + jcol];
        Wo[kk] = Wiouh[(size_t)k*768 + 256 + jcol];
        Wu[kk] = Wiouh[(size_t)k*768 + 512 + jcol];
        Wf[kk] = Wfh[(size_t)k*256 + jcol];
    }
    if (tid < 48)      biofL[tid] = biouh[(tid>>4)*256 + slice + (tid&15)];
    else if (tid < 64) biofL[tid] = bfh[slice + (tid - 48)];

    // ---- ioux/fx slice -> LDS ----
    {
        int n = tid >> 1, part = tid & 1;
        const float4* src4 = (const float4*)(iosrc + (size_t)n*64) + part*8;
        #pragma unroll
        for (int ii = 0; ii < 8; ii++){
            float4 v = src4[ii];
            int c0 = (part*8 + ii)*4;
            ioufL[n][c0+0]=v.x; ioufL[n][c0+1]=v.y; ioufL[n][c0+2]=v.z; ioufL[n][c0+3]=v.w;
        }
    }

    // ---- tree structure (block-local, deterministic) ----
    if (tid < 128){ par[tid] = parents[tid]; rnd[tid] = 0; }
    __syncthreads();
    for(;;){
        if (tid==0) changed = 0;
        __syncthreads();
        if (tid < 128){
            int p = par[tid];
            if (p < 128){
                int v = rnd[tid] + 1;
                if (atomicMax(&rnd[p], v) < v) changed = 1;
            }
        }
        __syncthreads();
        int done = (changed == 0);
        __syncthreads();
        if (done) break;
    }
    int nr = rnd[127] + 1;

    if (tid <= 128) cnt[tid] = 0;
    __syncthreads();
    if (tid < 128) atomicAdd(&cnt[rnd[tid]], 1);
    __syncthreads();
    if (tid==0){ int s2=0; for(int r2=0;r2<128;r2++){ rstart[r2]=s2; s2+=cnt[r2]; } rstart[128]=s2; }
    __syncthreads();
    if (tid < 128){
        int r2 = rnd[tid], rk = 0;
        for (int t2 = 0; t2 < tid; t2++) rk += (rnd[t2]==r2);
        order[rstart[r2]+rk] = tid;
    }
    __syncthreads();
    if (tid <= 128) cnt[tid] = 0;
    __syncthreads();
    if (tid < 128) atomicAdd(&cnt[par[tid]], 1);
    __syncthreads();
    if (tid==0){ int s2=0; for(int t2=0;t2<=128;t2++){ kstart[t2]=s2; s2+=cnt[t2]; } }
    __syncthreads();
    if (tid < 128){
        int p = par[tid], rk = 0;
        for (int t2 = 0; t2 < tid; t2++) rk += (par[t2]==p);
        kids[kstart[p]+rk] = tid;
    }
    __syncthreads();

    float bio0 = biofL[j], bio1 = biofL[16+j], bio2 = biofL[32+j];

    // ---- main level loop ----
    for (int r = 0; r < nr; r++){
        int rs = rstart[r], re = rstart[r+1];
        if (r == 0){
            // leaves: elementwise on ioux
            for (int b0 = rs; b0 < re; b0 += 16){
                int t = (b0 + a < re) ? order[b0 + a] : -1;
                float h = 0.f;
                if (t >= 0){
                    float iv = ioufL[t][j]    + bio0;
                    float ov = ioufL[t][16+j] + bio1;
                    float uv = ioufL[t][32+j] + bio2;
                    float cv = sigmf(iv) * tanh_fast(uv);
                    h = sigmf(ov) * tanh_fast(cv);
                    cc[t][j] = cv;
                }
                float hp = __shfl_xor(h, 1);
                if (t >= 0 && (j & 1) == 0)
                    astore(&H2[(size_t)t*128 + (slice>>1) + (j>>1)], packf2(h, hp));
            }
        } else {
            for (int b0 = rs; b0 < re; b0 += 16){
                int nn = re - b0; if (nn > 16) nn = 16;
                #pragma unroll
                for (int kk = 0; kk < 17; kk++) hsin[a][j*17+kk] = 0.f;
                fcin[a][j] = 0.f;
                if (tid == 0){
                    int s2 = 0;
                    for (int i2 = 0; i2 < 16; i2++){
                        coff[i2] = s2;
                        if (i2 < nn){ int t2 = order[b0+i2]; s2 += kstart[t2+1]-kstart[t2]; }
                    }
                    coff[16] = s2;
                }
                __syncthreads();
                if (tid < nn){
                    int t2 = order[b0+tid];
                    int o = coff[tid];
                    for (int ci = kstart[t2]; ci < kstart[t2+1]; ci++, o++){
                        clist[o] = kids[ci]; cslot[o] = tid; cpar[o] = t2;
                    }
                }
                __syncthreads();
                int M = coff[16];

                for (int cb = 0; cb < M; cb += 32){
                    int mm = M - cb; if (mm > 32) mm = 32;
                    {   // load child h rows via relaxed agent atomics
                        int s8 = tid >> 3, q8 = tid & 7;
                        if (s8 < mm){
                            int ch = clist[cb + s8];
                            unsigned long long* row = &H2[(size_t)ch*128 + q8*16];
                            #pragma unroll
                            for (int ii = 0; ii < 16; ii++){
                                union{ unsigned long long u; float f[2]; } w2;
                                w2.u = aload(&row[ii]);
                                int k = q8*32 + ii*2;
                                int km = (k>>4)*17 + (k&15);
                                hv[s8][km]   = w2.f[0];
                                hv[s8][km+1] = w2.f[1];
                            }
                        }
                    }
                    __syncthreads();
                    // f matvec (two halves of 16 slots to cap VGPRs)
                    #pragma unroll
                    for (int half = 0; half < 2; half++){
                        float af[16];
                        #pragma unroll
                        for (int s = 0; s < 16; s++){
                            float acc2 = 0.f;
                            const float* row = &hv[half*16 + s][a*17];
                            #pragma unroll
                            for (int kk = 0; kk < 16; kk++) acc2 = fmaf(Wf[kk], row[kk], acc2);
                            af[s] = acc2;
                        }
                        #pragma unroll
                        for (int s = 0; s < 16; s++){
                            af[s] += __shfl_xor(af[s], 16);
                            af[s] += __shfl_xor(af[s], 32);
                        }
                        if ((a & 3) == 0){
                            int w = tid >> 6;
                            #pragma unroll
                            for (int s = 0; s < 16; s++) red[w][half*16 + s][j] = af[s];
                        }
                    }
                    __syncthreads();
                    {   // f-gates -> FCtmp
                        int s = tid >> 3, jh = tid & 7;
                        if (s < mm){
                            int o = cb + s;
                            int p = cpar[o], ch = clist[o];
                            #pragma unroll
                            for (int e = 0; e < 2; e++){
                                int j2 = jh*2 + e;
                                float sf = red[0][s][j2]+red[1][s][j2]+red[2][s][j2]+red[3][s][j2];
                                float f = sigmf(sf + biofL[48+j2] + ioufL[p][48+j2]);
                                FCtmp[s][j2] = f * cc[ch][j2];
                            }
                        }
                    }
                    __syncthreads();
                    {   // accumulate into parent slots (fixed order: slot order)
                        int o0 = coff[a] > cb ? coff[a] : cb;
                        int o1 = coff[a+1] < cb+mm ? coff[a+1] : cb+mm;
                        for (int o = o0; o < o1; o++){
                            int s = o - cb;
                            #pragma unroll
                            for (int kk = 0; kk < 16; kk++)
                                hsin[a][j*17+kk] += hv[s][j*17+kk];
                            fcin[a][j] += FCtmp[s][j];
                        }
                    }
                    __syncthreads();
                }

                // iou matvec
                float ai[16], ao[16], au[16];
                #pragma unroll
                for (int n = 0; n < 16; n++){
                    float x=0.f, y=0.f, z=0.f;
                    const float* row = &hsin[n][a*17];
                    #pragma unroll
                    for (int kk = 0; kk < 16; kk++){
                        float v = row[kk];
                        x = fmaf(Wi[kk], v, x);
                        y = fmaf(Wo[kk], v, y);
                        z = fmaf(Wu[kk], v, z);
                    }
                    ai[n]=x; ao[n]=y; au[n]=z;
                }
                #pragma unroll
                for (int n = 0; n < 16; n++){
                    ai[n] += __shfl_xor(ai[n],16); ai[n] += __shfl_xor(ai[n],32);
                    ao[n] += __shfl_xor(ao[n],16); ao[n] += __shfl_xor(ao[n],32);
                    au[n] += __shfl_xor(au[n],16); au[n] += __shfl_xor(au[n],32);
                }
                if ((a & 3) == 0){
                    int w = tid >> 6;
                    #pragma unroll
                    for (int n = 0; n < 16; n++){
                        red[w][n][j]    = ai[n];
                        red[w][16+n][j] = ao[n];
                        red[w][32+n][j] = au[n];
                    }
                }
                __syncthreads();
                {   // gates -> h, c; publish h
                    int t = (a < nn) ? order[b0+a] : -1;
                    float h = 0.f;
                    if (t >= 0){
                        float si = red[0][a][j]+red[1][a][j]+red[2][a][j]+red[3][a][j];
                        float so = red[0][16+a][j]+red[1][16+a][j]+red[2][16+a][j]+red[3][16+a][j];
                        float su = red[0][32+a][j]+red[1][32+a][j]+red[2][32+a][j]+red[3][32+a][j];
                        float iv = si + ioufL[t][j]    + bio0;
                        float ov = so + ioufL[t][16+j] + bio1;
                        float uv = su + ioufL[t][32+j] + bio2;
                        float cv = fmaf(sigmf(iv), tanh_fast(uv), fcin[a][j]);
                        h = sigmf(ov) * tanh_fast(cv);
                        cc[t][j] = cv;
                    }
                    float hp = __shfl_xor(h, 1);
                    if (t >= 0 && (j&1)==0)
                        astore(&H2[(size_t)t*128 + (slice>>1) + (j>>1)], packf2(h, hp));
                }
                __syncthreads();
            }
        }

        if (r < nr-1){
            __syncthreads();    // drains each wave's vmcnt(0) -> H2 stores complete
            if (tid == 0){
                __hip_atomic_fetch_add(&barT[r], 1, __ATOMIC_RELAXED, __HIP_MEMORY_SCOPE_AGENT);
                while (__hip_atomic_load(&barT[r], __ATOMIC_RELAXED, __HIP_MEMORY_SCOPE_AGENT) < NBT){}
            }
            __syncthreads();
        }
    }

    // ---- fin barrier + fused head (block 0 only) ----
    __syncthreads();
    if (tid == 0)
        __hip_atomic_fetch_add(fin, 1, __ATOMIC_RELAXED, __HIP_MEMORY_SCOPE_AGENT);
    if (bid != 0) return;
    if (tid == 0){
        while (__hip_atomic_load(fin, __ATOMIC_RELAXED, __HIP_MEMORY_SCOPE_AGENT) < 32){}
    }
    __syncthreads();

    float* F  = (float*)hv;
    float* rl = F,        *rr  = F + 256;
    float* sA = F + 512,  *sB  = F + 640;
    float* bet= F + 768,  *alp = F + 1024;
    float* vl = F + 1280, *vr  = F + 1536;
    float* vec= F + 1792, *hid = F + 2304;

    {   // roots
        union{ unsigned long long u; float f[2]; } w2;
        if (tid < 128){
            w2.u = aload(&H2all[(size_t)127*128 + tid]);
            rl[tid*2] = w2.f[0]; rl[tid*2+1] = w2.f[1];
        } else {
            int p = tid - 128;
            w2.u = aload(&H2all[(size_t)(128+127)*128 + p]);
            rr[p*2] = w2.f[0]; rr[p*2+1] = w2.f[1];
        }
    }
    __syncthreads();
    {   // sA[j] = Hl_root . Hr[j] ; sB[i] = Hl[i] . Hr_root
        int i = tid & 127;
        unsigned long long* row = H2all + (size_t)((tid < 128) ? (128 + i) : i)*128;
        const float* rt = (tid < 128) ? rl : rr;
        float acc2 = 0.f;
        for (int p = 0; p < 128; p++){
            union{ unsigned long long u; float f[2]; } w2;
            w2.u = aload(&row[p]);
            acc2 = fmaf(w2.f[0], rt[2*p], acc2);
            acc2 = fmaf(w2.f[1], rt[2*p+1], acc2);
        }
        if (tid < 128) sA[i] = acc2; else sB[i] = acc2;
    }
    __syncthreads();
    if (tid < 2){
        float* v = tid ? sB : sA;
        float m = -1e30f;
        for (int k = 0; k < 128; k++) m = fmaxf(m, v[k]);
        float su2 = 0.f;
        for (int k = 0; k < 128; k++){ float e = __expf(v[k]-m); v[k]=e; su2+=e; }
        float inv = 1.0f/su2;
        for (int k = 0; k < 128; k++) v[k] *= inv;
    }
    __syncthreads();
    {   // bet = sA @ Hr ; alp = sB @ Hl
        int p = tid & 127;
        unsigned long long* base = H2all + ((tid < 128) ? (size_t)128*128 : 0);
        const float* wgt = (tid < 128) ? sA : sB;
        float b0 = 0.f, b1 = 0.f;
        for (int j2 = 0; j2 < 128; j2++){
            union{ unsigned long long u; float f[2]; } w2;
            w2.u = aload(&base[(size_t)j2*128 + p]);
            b0 = fmaf(wgt[j2], w2.f[0], b0);
            b1 = fmaf(wgt[j2], w2.f[1], b1);
        }
        float* dst = (tid < 128) ? bet : alp;
        dst[2*p] = b0; dst[2*p+1] = b1;
    }
    __syncthreads();
    {
        float x = 0.f, y = 0.f;
        for (int k = 0; k < 256; k++){
            float w = Wattn[(size_t)k*256 + tid];
            x = fmaf(rl[k], w, x);
            y = fmaf(rr[k], w, y);
        }
        for (int k = 0; k < 256; k++){
            float w = Wattn[(size_t)(256+k)*256 + tid];
            x = fmaf(bet[k], w, x);
            y = fmaf(alp[k], w, y);
        }
        vl[tid] = x + battn[tid];
        vr[tid] = y + battn[tid];
    }
    __syncthreads();
    vec[tid]       = vl[tid]*vr[tid];
    vec[256+tid]   = fabsf(vl[tid]-vr[tid]);
    __syncthreads();
    if (tid < 128){
        float acc2 = 0.f;
        for (int k = 0; k < 512; k++) acc2 = fmaf(vec[k], Wwh[(size_t)k*128+tid], acc2);
        hid[tid] = sigmf(acc2 + bwh[tid]);
    }
    __syncthreads();
    if (tid == 0){
        float lg[5];
        for (int c2 = 0; c2 < 5; c2++){
            float acc2 = bwp[c2];
            for (int k = 0; k < 128; k++) acc2 = fmaf(hid[k], Wwp[k*5+c2], acc2);
            lg[c2] = acc2;
        }
        float m = lg[0];
        for (int c2 = 1; c2 < 5; c2++) m = fmaxf(m, lg[c2]);
        float su2 = 0.f;
        for (int c2 = 0; c2 < 5; c2++) su2 += __expf(lg[c2]-m);
        float ls = logf(su2);
        for (int c2 = 0; c2 < 5; c2++) out[c2] = lg[c2]-m-ls;
    }
}

extern "C" void kernel_launch(void* const* d_in, const int* in_sizes, int n_in,
                              void* d_out, int out_size, void* d_ws, size_t ws_size,
                              hipStream_t stream) {
    const float* emb    = (const float*)d_in[0];
    const float* Wioux  = (const float*)d_in[1];
    const float* bioux  = (const float*)d_in[2];
    const float* Wiouh  = (const float*)d_in[3];
    const float* biouh  = (const float*)d_in[4];
    const float* Wfx    = (const float*)d_in[5];
    const float* bfx    = (const float*)d_in[6];
    const float* Wfh    = (const float*)d_in[7];
    const float* bfh    = (const float*)d_in[8];
    const float* Wattn  = (const float*)d_in[9];
    const float* battn  = (const float*)d_in[10];
    const float* Wwh    = (const float*)d_in[11];
    const float* bwh    = (const float*)d_in[12];
    const float* Wwp    = (const float*)d_in[13];
    const float* bwp    = (const float*)d_in[14];
    const int* linputs  = (const int*)d_in[15];
    const int* lparents = (const int*)d_in[16];
    const int* rinputs  = (const int*)d_in[17];
    const int* rparents = (const int*)d_in[18];
    float* ws  = (float*)d_ws;
    float* out = (float*)d_out;

    hipMemsetAsync((char*)d_ws + BAR_BYTE, 0, 2048, stream);
    k1_gemm<<<128, 256, 0, stream>>>(emb, Wioux, bioux, Wfx, bfx,
                                     linputs, rinputs, ws);
    k2_scan<<<32, 256, 0, stream>>>(Wiouh, biouh, Wfh, bfh, lparents, rparents,
                                    Wattn, battn, Wwh, bwh, Wwp, bwp, ws, out);
}

// Round 5
// 242.541 us; speedup vs baseline: 1.1438x; 1.1131x over previous
//
#include <hip/hip_runtime.h>
#include <math.h>

#define NBT 16

// ws byte offsets
#define H2_BYTE   0           // ull[2][128][128]  = 256 KB  (h pairs, atomic-only)
#define IOUX_BYTE 262144      // float[2][16][128][64] = 1 MB (k1 -> k2, block-grouped)
#define BAR_BYTE  1310720     // int[512]: [tree][128] level counters + fin at [256]

__device__ __forceinline__ float sigmf(float x){ return 1.0f/(1.0f+__expf(-x)); }
__device__ __forceinline__ float tanh_fast(float x){ float e=__expf(2.0f*x); return 1.0f - 2.0f/(e+1.0f); }
__device__ __forceinline__ unsigned long long packf2(float lo, float hi){
    union{ float f[2]; unsigned long long u; } x; x.f[0]=lo; x.f[1]=hi; return x.u;
}
__device__ __forceinline__ unsigned long long aload(unsigned long long* p){
    return __hip_atomic_load(p, __ATOMIC_RELAXED, __HIP_MEMORY_SCOPE_AGENT);
}
__device__ __forceinline__ void astore(unsigned long long* p, unsigned long long v){
    __hip_atomic_store(p, v, __ATOMIC_RELAXED, __HIP_MEMORY_SCOPE_AGENT);
}

// ---------------------------------------------------------------------------
// K1: input GEMM. 128 blocks = tree(2) x sub(16) x q(4); 256 threads.
// ---------------------------------------------------------------------------
__global__ __launch_bounds__(256) void k1_gemm(
        const float* __restrict__ emb,
        const float* __restrict__ Wioux, const float* __restrict__ bioux,
        const float* __restrict__ Wfx,   const float* __restrict__ bfx,
        const int* __restrict__ linputs, const int* __restrict__ rinputs,
        float* __restrict__ ws){
    int bid  = blockIdx.x;
    int tree = bid >> 6;
    int sub  = (bid >> 2) & 15;
    int q    = bid & 3;
    int n0   = q * 32;
    const int* inp = tree ? rinputs : linputs;
    float* dst = (float*)((char*)ws + IOUX_BYTE) + (size_t)(tree*16+sub)*128*64;

    __shared__ float Xs[32][513];
    __shared__ int toks[32];
    int tid = threadIdx.x;
    if (tid < 32) toks[tid] = inp[n0 + tid];
    __syncthreads();
    {
        int r = tid & 31, seg = tid >> 5;
        const float* src = emb + (size_t)toks[r]*512 + seg*64;
        #pragma unroll
        for (int ii = 0; ii < 16; ii++){
            float4 v = ((const float4*)src)[ii];
            Xs[r][seg*64 + ii*4 + 0] = v.x;
            Xs[r][seg*64 + ii*4 + 1] = v.y;
            Xs[r][seg*64 + ii*4 + 2] = v.z;
            Xs[r][seg*64 + ii*4 + 3] = v.w;
        }
    }
    __syncthreads();
    int c  = tid & 63;
    int ng = tid >> 6;
    int g = c >> 4, jj = c & 15;
    const float* Wcol; int ld; float bias;
    if (g < 3){ int col = g*256 + sub*16 + jj; Wcol = Wioux + col; ld = 768; bias = bioux[col]; }
    else      { int col = sub*16 + jj;         Wcol = Wfx + col;   ld = 256; bias = bfx[col]; }
    float acc[8] = {0,0,0,0,0,0,0,0};
    #pragma unroll 4
    for (int k = 0; k < 512; k++){
        float w = Wcol[(size_t)k*ld];
        #pragma unroll
        for (int i = 0; i < 8; i++) acc[i] = fmaf(Xs[ng*8+i][k], w, acc[i]);
    }
    #pragma unroll
    for (int i = 0; i < 8; i++)
        dst[(size_t)(n0 + ng*8 + i)*64 + c] = acc[i] + bias;
}

// ---------------------------------------------------------------------------
// K2: level-order TreeLSTM, 32 blocks (16/tree) x 256 threads, fused head.
// Exchange: relaxed agent atomics, COALESCED lane-major, one-shot per-level
// staging into LDS (each child row loaded exactly once per consumer block).
// ---------------------------------------------------------------------------
__global__ __launch_bounds__(256, 1) void k2_scan(
        const float* __restrict__ Wiouh, const float* __restrict__ biouh,
        const float* __restrict__ Wfh,   const float* __restrict__ bfh,
        const int* __restrict__ lparents, const int* __restrict__ rparents,
        const float* __restrict__ Wattn, const float* __restrict__ battn,
        const float* __restrict__ Wwh,   const float* __restrict__ bwh,
        const float* __restrict__ Wwp,   const float* __restrict__ bwp,
        float* __restrict__ ws, float* __restrict__ out){

    int bid = blockIdx.x;
    int tree = bid >> 4;
    int sub  = bid & 15;
    int slice = sub * 16;
    const int* parents = tree ? rparents : lparents;

    unsigned long long* H2all = (unsigned long long*)((char*)ws + H2_BYTE);
    unsigned long long* H2 = H2all + (size_t)tree*128*128;
    const float* iosrc = (const float*)((char*)ws + IOUX_BYTE) + (size_t)(tree*16+sub)*128*64;
    int* bar  = (int*)((char*)ws + BAR_BYTE);
    int* barT = bar + tree*128;
    int* fin  = bar + 256;

    __shared__ float hv[64][272];        // staged child rows, km = (k>>4)*17+(k&15)
    __shared__ float red[4][64][17];     // cross-wave reduce; red[0] doubles as FCtmp
    __shared__ float hsin[16][272];      // per-node child-h sums
    __shared__ float cc[128][17];        // c (own cols) per node
    __shared__ float ioufL[128][67];     // 0..47 = i|o|u slice, 48..63 = fx slice
    __shared__ float biofL[64];
    __shared__ int par[128], rnd[128], order[128], kids[128];
    __shared__ int rstart[129], kstart[129], cnt[129];
    __shared__ int clist[128], cpar[128];
    __shared__ int coff[17];
    __shared__ int changed;

    int tid = threadIdx.x;
    int a = tid >> 4;       // k-group / node-slot
    int j = tid & 15;
    int jcol = slice + j;

    // ---- recurrence weights -> registers (whole kernel) ----
    float Wi[16], Wo[16], Wu[16], Wf[16];
    #pragma unroll
    for (int kk = 0; kk < 16; kk++){
        int k = a*16 + kk;
        Wi[kk] = Wiouh[(size_t)k*768 + jcol];
        Wo[kk] = Wiouh[(size_t)k*768 + 256 + jcol];
        Wu[kk] = Wiouh[(size_t)k*768 + 512 + jcol];
        Wf[kk] = Wfh[(size_t)k*256 + jcol];
    }
    if (tid < 48)      biofL[tid] = biouh[(tid>>4)*256 + slice + (tid&15)];
    else if (tid < 64) biofL[tid] = bfh[slice + (tid - 48)];

    // ---- ioux/fx slice -> LDS ----
    {
        int n = tid >> 1, part = tid & 1;
        const float4* src4 = (const float4*)(iosrc + (size_t)n*64) + part*8;
        #pragma unroll
        for (int ii = 0; ii < 8; ii++){
            float4 v = src4[ii];
            int c0 = (part*8 + ii)*4;
            ioufL[n][c0+0]=v.x; ioufL[n][c0+1]=v.y; ioufL[n][c0+2]=v.z; ioufL[n][c0+3]=v.w;
        }
    }

    // ---- tree structure (block-local, deterministic) ----
    if (tid < 128){ par[tid] = parents[tid]; rnd[tid] = 0; }
    __syncthreads();
    for(;;){
        if (tid==0) changed = 0;
        __syncthreads();
        if (tid < 128){
            int p = par[tid];
            if (p < 128){
                int v = rnd[tid] + 1;
                if (atomicMax(&rnd[p], v) < v) changed = 1;
            }
        }
        __syncthreads();
        int done = (changed == 0);
        __syncthreads();
        if (done) break;
    }
    int nr = rnd[127] + 1;

    if (tid <= 128) cnt[tid] = 0;
    __syncthreads();
    if (tid < 128) atomicAdd(&cnt[rnd[tid]], 1);
    __syncthreads();
    if (tid==0){ int s2=0; for(int r2=0;r2<128;r2++){ rstart[r2]=s2; s2+=cnt[r2]; } rstart[128]=s2; }
    __syncthreads();
    if (tid < 128){
        int r2 = rnd[tid], rk = 0;
        for (int t2 = 0; t2 < tid; t2++) rk += (rnd[t2]==r2);
        order[rstart[r2]+rk] = tid;
    }
    __syncthreads();
    if (tid <= 128) cnt[tid] = 0;
    __syncthreads();
    if (tid < 128) atomicAdd(&cnt[par[tid]], 1);
    __syncthreads();
    if (tid==0){ int s2=0; for(int t2=0;t2<=128;t2++){ kstart[t2]=s2; s2+=cnt[t2]; } }
    __syncthreads();
    if (tid < 128){
        int p = par[tid], rk = 0;
        for (int t2 = 0; t2 < tid; t2++) rk += (par[t2]==p);
        kids[kstart[p]+rk] = tid;
    }
    __syncthreads();

    float bio0 = biofL[j], bio1 = biofL[16+j], bio2 = biofL[32+j];

    // ---- main level loop ----
    for (int r = 0; r < nr; r++){
        int rs = rstart[r], re = rstart[r+1];
        if (r == 0){
            for (int b0 = rs; b0 < re; b0 += 16){
                int t = (b0 + a < re) ? order[b0 + a] : -1;
                float h = 0.f;
                if (t >= 0){
                    float iv = ioufL[t][j]    + bio0;
                    float ov = ioufL[t][16+j] + bio1;
                    float uv = ioufL[t][32+j] + bio2;
                    float cv = sigmf(iv) * tanh_fast(uv);
                    h = sigmf(ov) * tanh_fast(cv);
                    cc[t][j] = cv;
                }
                float hp = __shfl_xor(h, 1);
                if (t >= 0 && (j & 1) == 0)
                    astore(&H2[(size_t)t*128 + (slice>>1) + (j>>1)], packf2(h, hp));
            }
        } else {
            for (int b0 = rs; b0 < re; b0 += 16){
                int nn = re - b0; if (nn > 16) nn = 16;
                #pragma unroll
                for (int kk = 0; kk < 17; kk++) hsin[a][j*17+kk] = 0.f;
                float fc = 0.f;
                if (tid == 0){
                    int s2 = 0;
                    for (int i2 = 0; i2 < 16; i2++){
                        coff[i2] = s2;
                        if (i2 < nn){ int t2 = order[b0+i2]; s2 += kstart[t2+1]-kstart[t2]; }
                    }
                    coff[16] = s2;
                }
                __syncthreads();
                if (tid < nn){
                    int t2 = order[b0+tid];
                    int o = coff[tid];
                    for (int ci = kstart[t2]; ci < kstart[t2+1]; ci++, o++){
                        clist[o] = kids[ci]; cpar[o] = t2;
                    }
                }
                __syncthreads();
                int M = coff[16];

                for (int cb = 0; cb < M; cb += 64){
                    int mm = M - cb; if (mm > 64) mm = 64;

                    // ---- stage mm child rows: coalesced lane-major, 16-deep ----
                    {
                        int half = tid >> 7;          // 0/1: which row of the pair
                        int u7   = tid & 127;         // ull index within row
                        int k0   = u7 * 2;
                        int km   = (k0 >> 4)*17 + (k0 & 15);
                        #pragma unroll 1
                        for (int it0 = 0; it0 < 32; it0 += 16){
                            unsigned long long u[16];
                            #pragma unroll
                            for (int q = 0; q < 16; q++){
                                int row = (it0 + q)*2 + half;
                                u[q] = 0ull;
                                if (row < mm)
                                    u[q] = aload(&H2[(size_t)clist[cb+row]*128 + u7]);
                            }
                            #pragma unroll
                            for (int q = 0; q < 16; q++){
                                int row = (it0 + q)*2 + half;
                                if (row < mm){
                                    union{ unsigned long long uu; float f[2]; } w2; w2.uu = u[q];
                                    hv[row][km]   = w2.f[0];
                                    hv[row][km+1] = w2.f[1];
                                }
                            }
                        }
                    }
                    __syncthreads();

                    // ---- f matvec: passes of 32 slots ----
                    for (int p0 = 0; p0 < mm; p0 += 32){
                        float af[32];
                        #pragma unroll
                        for (int s = 0; s < 32; s++){
                            float acc2 = 0.f;
                            const float* row = &hv[p0+s][a*17];
                            #pragma unroll
                            for (int kk = 0; kk < 16; kk++) acc2 = fmaf(Wf[kk], row[kk], acc2);
                            af[s] = acc2;
                        }
                        #pragma unroll
                        for (int s = 0; s < 32; s++){
                            af[s] += __shfl_xor(af[s], 16);
                            af[s] += __shfl_xor(af[s], 32);
                        }
                        if ((a & 3) == 0){
                            int w = tid >> 6;
                            #pragma unroll
                            for (int s = 0; s < 32; s++) red[w][p0+s][j] = af[s];
                        }
                    }
                    __syncthreads();

                    // ---- f gates -> FCtmp (aliases red[0]) ----
                    {
                        int s = tid >> 2;
                        if (s < mm){
                            int o = cb + s;
                            int pn = cpar[o], ch = clist[o];
                            #pragma unroll
                            for (int e = 0; e < 4; e++){
                                int j2 = (tid & 3)*4 + e;
                                float sf = red[0][s][j2]+red[1][s][j2]+red[2][s][j2]+red[3][s][j2];
                                float f = sigmf(sf + biofL[48+j2] + ioufL[pn][48+j2]);
                                red[0][s][j2] = f * cc[ch][j2];
                            }
                        }
                    }
                    __syncthreads();

                    // ---- accumulate into parent slots (fixed order) ----
                    {
                        int o0 = coff[a] > cb ? coff[a] : cb;
                        int o1 = coff[a+1] < cb+mm ? coff[a+1] : cb+mm;
                        float* dst = &hsin[a][j*17];
                        for (int o = o0; o < o1; o++){
                            int s = o - cb;
                            const float* src = &hv[s][j*17];
                            #pragma unroll
                            for (int kk = 0; kk < 16; kk++) dst[kk] += src[kk];
                            fc += red[0][s][j];
                        }
                    }
                    __syncthreads();
                }

                // ---- iou matvec ----
                float ai[16], ao[16], au[16];
                #pragma unroll
                for (int n = 0; n < 16; n++){
                    float x=0.f, y=0.f, z=0.f;
                    const float* row = &hsin[n][a*17];
                    #pragma unroll
                    for (int kk = 0; kk < 16; kk++){
                        float v = row[kk];
                        x = fmaf(Wi[kk], v, x);
                        y = fmaf(Wo[kk], v, y);
                        z = fmaf(Wu[kk], v, z);
                    }
                    ai[n]=x; ao[n]=y; au[n]=z;
                }
                #pragma unroll
                for (int n = 0; n < 16; n++){
                    ai[n] += __shfl_xor(ai[n],16); ai[n] += __shfl_xor(ai[n],32);
                    ao[n] += __shfl_xor(ao[n],16); ao[n] += __shfl_xor(ao[n],32);
                    au[n] += __shfl_xor(au[n],16); au[n] += __shfl_xor(au[n],32);
                }
                if ((a & 3) == 0){
                    int w = tid >> 6;
                    #pragma unroll
                    for (int n = 0; n < 16; n++){
                        red[w][n][j]    = ai[n];
                        red[w][16+n][j] = ao[n];
                        red[w][32+n][j] = au[n];
                    }
                }
                __syncthreads();
                {   // gates -> h, c; publish h
                    int t = (a < nn) ? order[b0+a] : -1;
                    float h = 0.f;
                    if (t >= 0){
                        float si = red[0][a][j]+red[1][a][j]+red[2][a][j]+red[3][a][j];
                        float so = red[0][16+a][j]+red[1][16+a][j]+red[2][16+a][j]+red[3][16+a][j];
                        float su = red[0][32+a][j]+red[1][32+a][j]+red[2][32+a][j]+red[3][32+a][j];
                        float iv = si + ioufL[t][j]    + bio0;
                        float ov = so + ioufL[t][16+j] + bio1;
                        float uv = su + ioufL[t][32+j] + bio2;
                        float cv = fmaf(sigmf(iv), tanh_fast(uv), fc);
                        h = sigmf(ov) * tanh_fast(cv);
                        cc[t][j] = cv;
                    }
                    float hp = __shfl_xor(h, 1);
                    if (t >= 0 && (j&1)==0)
                        astore(&H2[(size_t)t*128 + (slice>>1) + (j>>1)], packf2(h, hp));
                }
                __syncthreads();
            }
        }

        if (r < nr-1){
            __syncthreads();    // drains vmcnt -> all H2 stores complete
            if (tid == 0){
                __hip_atomic_fetch_add(&barT[r], 1, __ATOMIC_RELAXED, __HIP_MEMORY_SCOPE_AGENT);
                while (__hip_atomic_load(&barT[r], __ATOMIC_RELAXED, __HIP_MEMORY_SCOPE_AGENT) < NBT){}
            }
            __syncthreads();
        }
    }

    // ---- fin barrier + fused head (block 0 only) ----
    __syncthreads();
    if (tid == 0)
        __hip_atomic_fetch_add(fin, 1, __ATOMIC_RELAXED, __HIP_MEMORY_SCOPE_AGENT);
    if (bid != 0) return;
    if (tid == 0){
        while (__hip_atomic_load(fin, __ATOMIC_RELAXED, __HIP_MEMORY_SCOPE_AGENT) < 32){}
    }
    __syncthreads();

    float* F  = (float*)hv;
    float* rl = F,        *rr  = F + 256;
    float* sA = F + 512,  *sB  = F + 640;
    float* bet= F + 768,  *alp = F + 1024;
    float* vl = F + 1280, *vr  = F + 1536;
    float* vec= F + 1792, *hid = F + 2304;

    {   // roots
        union{ unsigned long long u; float f[2]; } w2;
        if (tid < 128){
            w2.u = aload(&H2all[(size_t)127*128 + tid]);
            rl[tid*2] = w2.f[0]; rl[tid*2+1] = w2.f[1];
        } else {
            int p = tid - 128;
            w2.u = aload(&H2all[(size_t)(128+127)*128 + p]);
            rr[p*2] = w2.f[0]; rr[p*2+1] = w2.f[1];
        }
    }
    __syncthreads();
    {   // sA[j] = Hl_root . Hr[j] ; sB[i] = Hl[i] . Hr_root
        int i = tid & 127;
        unsigned long long* row = H2all + (size_t)((tid < 128) ? (128 + i) : i)*128;
        const float* rt = (tid < 128) ? rl : rr;
        float acc2 = 0.f;
        for (int p = 0; p < 128; p++){
            union{ unsigned long long u; float f[2]; } w2;
            w2.u = aload(&row[p]);
            acc2 = fmaf(w2.f[0], rt[2*p], acc2);
            acc2 = fmaf(w2.f[1], rt[2*p+1], acc2);
        }
        if (tid < 128) sA[i] = acc2; else sB[i] = acc2;
    }
    __syncthreads();
    if (tid < 2){
        float* v = tid ? sB : sA;
        float m = -1e30f;
        for (int k = 0; k < 128; k++) m = fmaxf(m, v[k]);
        float su2 = 0.f;
        for (int k = 0; k < 128; k++){ float e = __expf(v[k]-m); v[k]=e; su2+=e; }
        float inv = 1.0f/su2;
        for (int k = 0; k < 128; k++) v[k] *= inv;
    }
    __syncthreads();
    {   // bet = sA @ Hr ; alp = sB @ Hl
        int p = tid & 127;
        unsigned long long* base = H2all + ((tid < 128) ? (size_t)128*128 : 0);
        const float* wgt = (tid < 128) ? sA : sB;
        float b0 = 0.f, b1 = 0.f;
        for (int j2 = 0; j2 < 128; j2++){
            union{ unsigned long long u; float f[2]; } w2;
            w2.u = aload(&base[(size_t)j2*128 + p]);
            b0 = fmaf(wgt[j2], w2.f[0], b0);
            b1 = fmaf(wgt[j2], w2.f[1], b1);
        }
        float* dst = (tid < 128) ? bet : alp;
        dst[2*p] = b0; dst[2*p+1] = b1;
    }
    __syncthreads();
    {
        float x = 0.f, y = 0.f;
        for (int k = 0; k < 256; k++){
            float w = Wattn[(size_t)k*256 + tid];
            x = fmaf(rl[k], w, x);
            y = fmaf(rr[k], w, y);
        }
        for (int k = 0; k < 256; k++){
            float w = Wattn[(size_t)(256+k)*256 + tid];
            x = fmaf(bet[k], w, x);
            y = fmaf(alp[k], w, y);
        }
        vl[tid] = x + battn[tid];
        vr[tid] = y + battn[tid];
    }
    __syncthreads();
    vec[tid]       = vl[tid]*vr[tid];
    vec[256+tid]   = fabsf(vl[tid]-vr[tid]);
    __syncthreads();
    if (tid < 128){
        float acc2 = 0.f;
        for (int k = 0; k < 512; k++) acc2 = fmaf(vec[k], Wwh[(size_t)k*128+tid], acc2);
        hid[tid] = sigmf(acc2 + bwh[tid]);
    }
    __syncthreads();
    if (tid == 0){
        float lg[5];
        for (int c2 = 0; c2 < 5; c2++){
            float acc2 = bwp[c2];
            for (int k = 0; k < 128; k++) acc2 = fmaf(hid[k], Wwp[k*5+c2], acc2);
            lg[c2] = acc2;
        }
        float m = lg[0];
        for (int c2 = 1; c2 < 5; c2++) m = fmaxf(m, lg[c2]);
        float su2 = 0.f;
        for (int c2 = 0; c2 < 5; c2++) su2 += __expf(lg[c2]-m);
        float ls = logf(su2);
        for (int c2 = 0; c2 < 5; c2++) out[c2] = lg[c2]-m-ls;
    }
}

extern "C" void kernel_launch(void* const* d_in, const int* in_sizes, int n_in,
                              void* d_out, int out_size, void* d_ws, size_t ws_size,
                              hipStream_t stream) {
    const float* emb    = (const float*)d_in[0];
    const float* Wioux  = (const float*)d_in[1];
    const float* bioux  = (const float*)d_in[2];
    const float* Wiouh  = (const float*)d_in[3];
    const float* biouh  = (const float*)d_in[4];
    const float* Wfx    = (const float*)d_in[5];
    const float* bfx    = (const float*)d_in[6];
    const float* Wfh    = (const float*)d_in[7];
    const float* bfh    = (const float*)d_in[8];
    const float* Wattn  = (const float*)d_in[9];
    const float* battn  = (const float*)d_in[10];
    const float* Wwh    = (const float*)d_in[11];
    const float* bwh    = (const float*)d_in[12];
    const float* Wwp    = (const float*)d_in[13];
    const float* bwp    = (const float*)d_in[14];
    const int* linputs  = (const int*)d_in[15];
    const int* lparents = (const int*)d_in[16];
    const int* rinputs  = (const int*)d_in[17];
    const int* rparents = (const int*)d_in[18];
    float* ws  = (float*)d_ws;
    float* out = (float*)d_out;

    hipMemsetAsync((char*)d_ws + BAR_BYTE, 0, 2048, stream);
    k1_gemm<<<128, 256, 0, stream>>>(emb, Wioux, bioux, Wfx, bfx,
                                     linputs, rinputs, ws);
    k2_scan<<<32, 256, 0, stream>>>(Wiouh, biouh, Wfh, bfh, lparents, rparents,
                                    Wattn, battn, Wwh, bwh, Wwp, bwp, ws, out);
}